// Round 12
// baseline (4580.452 us; speedup 1.0000x reference)
//
#include <hip/hip_runtime.h>
#include <math.h>

constexpr int kB  = 256;
constexpr int kT  = 512;
constexpr int kNS = 64;
constexpr int kH  = 128;

__device__ __forceinline__ float sigmoidf_(float v) { return 1.0f / (1.0f + __expf(-v)); }
__device__ __forceinline__ float dot4(float4 a, float4 b) {
    return a.x*b.x + a.y*b.y + a.z*b.z + a.w*b.w;
}

// One-time: transpose Whh[128][384] -> WhhT[384][128] in d_ws.
extern "C" __global__ void __launch_bounds__(256)
whh_transpose(const float* __restrict__ Whh, float* __restrict__ WhhT) {
    const int o = blockIdx.x * 256 + threadIdx.x;   // 0..49151
    const int j = o >> 7, k = o & 127;
    WhhT[o] = Whh[k * 384 + j];
}

// One block (512 threads) per batch row. 3 barriers/step:
//  P1: K + einsum + enc — FULLY wave-private (K passed via v_readlane, not
//      LDS; enc via uniform u32 max => SALU). No sh_K array at all.
//  P2: GRU (thr 0-127) | ns pre-reduce (thr 128-319) | prefetch (thr 320)
//  P3: w0 tail (pre-reduced ns) | w2-4 gh stream 2 rows/thr (h_{t+1})
extern "C" __global__ void __launch_bounds__(512, 2)
disc_kernel(const float* __restrict__ x,   const float* __restrict__ y,
            const float* __restrict__ U,   const float* __restrict__ S,
            const float* __restrict__ A,   const float* __restrict__ Wih,
            const float* __restrict__ bih, const float* __restrict__ bhh,
            const float* __restrict__ Wd,  const float* __restrict__ bd,
            const float* __restrict__ WhhT,
            float* __restrict__ out_o,  float* __restrict__ out_p)
{
    const int b    = blockIdx.x;
    const int tid  = threadIdx.x;
    const int lane = tid & 63;
    const int wid  = tid >> 6;
    const int hb   = tid & 1;

    __shared__ __align__(16) float sh_part[512];
    __shared__ __align__(16) float sh_part2[512];
    __shared__ __align__(16) float sh_ns[192];
    __shared__ __align__(16) float sh_gh[384];
    __shared__ __align__(16) float sh_h[2][kH];      // parity double buffer
    __shared__ __align__(16) float sh_s[kNS];
    __shared__ __align__(16) float sh_Wih[4 * 384];
    __shared__ __align__(16) float sh_bih[384];
    __shared__ __align__(16) float sh_bhh[384];
    __shared__ float sh_Wd[384];
    __shared__ float sh_bd[4];
    __shared__ float sh_encA[8];                     // per-wave max of kk_a
    __shared__ float sh_encB[8];                     // per-wave max of kk_b
    __shared__ __align__(16) float sh_xt[4];
    __shared__ float sh_x2, sh_s2, sh_err;
    __shared__ float sh_yt[2];

    // ---- Persistent register caches (identical layout to R11) ------------
    const float4* S4 = reinterpret_cast<const float4*>(S);
    const float4* U4 = reinterpret_cast<const float4*>(U);

    float4 Sa[16]; float4 Ua; float Ca;       // full K-row = tid
    float4 Sb[8];  float Ub0, Ub1; float Cb;  // half of K-row 512+(tid>>1)
    {
        float ss = 0.f;
#pragma unroll
        for (int j = 0; j < 16; ++j) { Sa[j] = S4[tid * 16 + j]; ss += dot4(Sa[j], Sa[j]); }
        Ua = U4[tid];
        Ca = -0.5f * (dot4(Ua, Ua) + ss);
    }
    const int pbrow = 512 + (tid >> 1);
    {
        float ss = 0.f;
#pragma unroll
        for (int j = 0; j < 8; ++j) { Sb[j] = S4[pbrow * 16 + hb * 8 + j]; ss += dot4(Sb[j], Sb[j]); }
        Ub0 = U[pbrow * 4 + hb * 2 + 0];
        Ub1 = U[pbrow * 4 + hb * 2 + 1];
        Cb = -0.5f * (Ub0*Ub0 + Ub1*Ub1 + ss);
    }
    // Einsum A caches — wave-uniform chunk mapping
    float A1[64];                              // row block [64*wid, 64*wid+64), n=lane
#pragma unroll
    for (int dd = 0; dd < 64; ++dd)
        A1[dd] = A[((wid >> 2) * 256 + (wid & 3) * 64 + dd) * 64 + lane];
    float A2[32];                              // rows [512+32*wid, +32), n=lane
#pragma unroll
    for (int dd = 0; dd < 32; ++dd)
        A2[dd] = A[(512 + (wid >> 1) * 64 + (wid & 1) * 32 + dd) * 64 + lane];

    // P3-wave0 persistent gate state
    float g0 = 0.3333f, g1 = 0.3333f, g2 = 0.3334f;

    // ---- LDS preload -----------------------------------------------------
    for (int i = tid; i < 1536; i += 512) sh_Wih[i] = Wih[i];
    for (int i = tid; i < 384; i += 512) {
        sh_bih[i] = bih[i];
        sh_bhh[i] = bhh[i];
        sh_gh[i]  = bhh[i];                   // gh(t=0) with h=0
        sh_Wd[i]  = (i < 381) ? Wd[i] : 0.f;  // zero-pad cols 381..383
    }
    if (tid < 3) sh_bd[tid] = bd[tid];
    if (tid < kNS) sh_s[tid] = 0.f;
    if (tid < kH)  sh_h[0][tid] = 0.f;
    if (tid == 0) {
        sh_err = 1.0f; sh_s2 = 0.f;
        float4 xv = reinterpret_cast<const float4*>(x)[(size_t)b * kT];
        reinterpret_cast<float4*>(sh_xt)[0] = xv;
        sh_x2 = dot4(xv, xv);
        sh_yt[0] = y[(size_t)b * kT];
    }
    __syncthreads();

    for (int t = 0; t < kT; ++t) {
        const int par  = t & 1;
        const int par1 = (t + 1) & 1;

        // ===== P1: K + einsum + enc, fully wave-private ====================
        {
            const float scal = -0.5f * (sh_x2 + sh_s2);
            const float4 xt4 = reinterpret_cast<const float4*>(sh_xt)[0];
            const float4* s4 = reinterpret_cast<const float4*>(sh_s);
            float da0 = 0.f, da1 = 0.f, dblo = 0.f, dbhi = 0.f;
#pragma unroll
            for (int j = 0; j < 8; ++j) {
                const float4 sv0 = s4[j];              // s[0..31]
                const float4 sv1 = s4[8 + j];          // s[32..63]
                da0  += dot4(sv0, Sa[j]);
                da1  += dot4(sv1, Sa[8 + j]);
                dblo += dot4(sv0, Sb[j]);              // pairing if hb==0
                dbhi += dot4(sv1, Sb[j]);              // pairing if hb==1
            }
            const float db = hb ? dbhi : dblo;
            const float kk_a = __expf(scal + Ca + dot4(xt4, Ua) + da0 + da1);
            const float xbp  = hb ? (xt4.z*Ub0 + xt4.w*Ub1) : (xt4.x*Ub0 + xt4.y*Ub1);
            const float ph   = db + Cb + xbp;
            const float po   = __shfl_xor(ph, 1, 64);
            const float kk_b = __expf(scal + ph + po);

            // einsum + max via readlane (no LDS round-trip for K)
            const unsigned ka_bits = __float_as_uint(kk_a);
            const unsigned kb_bits = __float_as_uint(kk_b);
            float acc = 0.f;
            unsigned mA = 0u;                          // kk > 0 => u32 order == f32 order
#pragma unroll
            for (int dd = 0; dd < 64; ++dd) {
                const unsigned kb = __builtin_amdgcn_readlane(ka_bits, dd);
                mA = (kb > mA) ? kb : mA;
                acc += __uint_as_float(kb) * A1[dd];
            }
            sh_part[tid] = acc;
            float accb = 0.f;
            unsigned mB = 0u;
#pragma unroll
            for (int dd = 0; dd < 32; ++dd) {
                const unsigned kb = __builtin_amdgcn_readlane(kb_bits, 2 * dd);
                mB = (kb > mB) ? kb : mB;
                accb += __uint_as_float(kb) * A2[dd];
            }
            sh_part2[tid] = accb;
            if (lane == 0) {
                sh_encA[wid] = __uint_as_float(mA);
                sh_encB[wid] = __uint_as_float(mB);
            }
        }
        __syncthreads();                                  // (1)

        // ===== P2: GRU (0-127) | ns reduce (128-319) | prefetch (320) ======
        if (tid < 128) {
            const float e0 = fmaxf(fmaxf(sh_encA[0], sh_encA[1]), fmaxf(sh_encA[2], sh_encA[3]));
            const float e1 = fmaxf(fmaxf(sh_encA[4], sh_encA[5]), fmaxf(sh_encA[6], sh_encA[7]));
            const float e2 = fmaxf(fmaxf(fmaxf(sh_encB[0], sh_encB[1]), fmaxf(sh_encB[2], sh_encB[3])),
                                   fmaxf(fmaxf(sh_encB[4], sh_encB[5]), fmaxf(sh_encB[6], sh_encB[7])));
            const float er = sh_err;
            const int j = tid;
            const float gir = sh_bih[j]       + e0*sh_Wih[j]        + e1*sh_Wih[384 + j]
                                              + e2*sh_Wih[768 + j]  + er*sh_Wih[1152 + j];
            const float giz = sh_bih[128 + j] + e0*sh_Wih[128 + j]  + e1*sh_Wih[512 + j]
                                              + e2*sh_Wih[896 + j]  + er*sh_Wih[1280 + j];
            const float gin = sh_bih[256 + j] + e0*sh_Wih[256 + j]  + e1*sh_Wih[640 + j]
                                              + e2*sh_Wih[1024 + j] + er*sh_Wih[1408 + j];
            const float r  = sigmoidf_(gir + sh_gh[j]);
            const float z  = sigmoidf_(giz + sh_gh[128 + j]);
            const float nn = tanhf(gin + r * sh_gh[256 + j]);
            sh_h[par1][j] = (1.f - z) * nn + z * sh_h[par][j];
        } else if (tid < 320) {
            const int idx = tid - 128;                     // 0..191: m = idx>>6, n = idx&63
            const int m = idx >> 6, n = idx & 63;
            float v;
            if (m == 0)
                v = (sh_part[n]        + sh_part[64 + n])
                  + (sh_part[128 + n]  + sh_part[192 + n]);
            else if (m == 1)
                v = (sh_part[256 + n]  + sh_part[320 + n])
                  + (sh_part[384 + n]  + sh_part[448 + n]);
            else
                v = ((sh_part2[n]        + sh_part2[64 + n])
                  +  (sh_part2[128 + n]  + sh_part2[192 + n]))
                  + ((sh_part2[256 + n]  + sh_part2[320 + n])
                  +  (sh_part2[384 + n]  + sh_part2[448 + n]));
            sh_ns[idx] = v;
        } else if (tid == 320) {
            if ((t + 1) < kT) {
                float4 xv = reinterpret_cast<const float4*>(x)[(size_t)b * kT + t + 1];
                reinterpret_cast<float4*>(sh_xt)[0] = xv;
                sh_x2 = dot4(xv, xv);
                sh_yt[par1] = y[(size_t)b * kT + t + 1];
            }
        }
        __syncthreads();                                  // (2)

        // ===== P3: w0 tail | w2-4 gh 2 rows/thr (h_{t+1}) ==================
        if (wid == 0) {
            const float hA = sh_h[par1][lane];
            const float hB = sh_h[par1][64 + lane];
            const float theta = sigmoidf_(sh_h[par1][127]);
            float l0 = hA * sh_Wd[lane*3+0] + hB * sh_Wd[(64+lane)*3+0];
            float l1 = hA * sh_Wd[lane*3+1] + hB * sh_Wd[(64+lane)*3+1];
            float l2 = hA * sh_Wd[lane*3+2] + hB * sh_Wd[(64+lane)*3+2];
#pragma unroll
            for (int o = 32; o > 0; o >>= 1) {
                l0 += __shfl_xor(l0, o, 64);
                l1 += __shfl_xor(l1, o, 64);
                l2 += __shfl_xor(l2, o, 64);
            }
            l0 += sh_bd[0]; l1 += sh_bd[1]; l2 += sh_bd[2];
            const float mx = fmaxf(l0, fmaxf(l1, l2));
            const float x0 = __expf(l0 - mx), x1 = __expf(l1 - mx), x2 = __expf(l2 - mx);
            const float inv = theta / (x0 + x1 + x2);
            const float omt = 1.f - theta;
            g0 = x0*inv + g0*omt;
            g1 = x1*inv + g1*omt;
            g2 = x2*inv + g2*omt;
            const float sn = g0*sh_ns[lane] + g1*sh_ns[64 + lane] + g2*sh_ns[128 + lane];
            sh_s[lane] = sn;
            if (lane == 0)
                out_p[(size_t)b * kT + t] = g0*(1.f-g0) + g1*(1.f-g1) + g2*(1.f-g2);
            if (lane == 63) {
                out_o[(size_t)b * kT + t] = sn;
                sh_err = sn - sh_yt[par];
            }
            float ss = sn * sn;
#pragma unroll
            for (int o = 32; o > 0; o >>= 1) ss += __shfl_xor(ss, o, 64);
            if (lane == 0) sh_s2 = ss;
        } else if (wid >= 2 && tid < 320) {                // waves 2-4: rows u, u+192
            const int u = tid - 128;                       // 0..191
            const float4* W4a = reinterpret_cast<const float4*>(WhhT) + u * 32;
            const float4* W4b = reinterpret_cast<const float4*>(WhhT) + (u + 192) * 32;
            const float4* h4  = reinterpret_cast<const float4*>(sh_h[par1]);
            float ga = sh_bhh[u], gb = sh_bhh[u + 192];
#pragma unroll 8
            for (int k4 = 0; k4 < 32; ++k4) {
                const float4 hv = h4[k4];                  // read h ONCE per pair
                ga += dot4(hv, W4a[k4]);
                gb += dot4(hv, W4b[k4]);
            }
            sh_gh[u] = ga;
            sh_gh[u + 192] = gb;
        }
        __syncthreads();                                  // (3)
    }
}

extern "C" void kernel_launch(void* const* d_in, const int* in_sizes, int n_in,
                              void* d_out, int out_size, void* d_ws, size_t ws_size,
                              hipStream_t stream)
{
    const float* x   = (const float*)d_in[0];
    const float* y   = (const float*)d_in[1];
    const float* U   = (const float*)d_in[2];
    const float* S   = (const float*)d_in[3];
    const float* A   = (const float*)d_in[4];
    const float* Wih = (const float*)d_in[5];
    const float* Whh = (const float*)d_in[6];
    const float* bih = (const float*)d_in[7];
    const float* bhh = (const float*)d_in[8];
    const float* Wd  = (const float*)d_in[9];
    const float* bd  = (const float*)d_in[10];

    float* WhhT  = (float*)d_ws;                 // 49152 floats = 192 KB scratch
    float* out_o = (float*)d_out;                // (B, T) preds
    float* out_p = out_o + kB * kT;              // (B, T, 1) penalties

    hipLaunchKernelGGL(whh_transpose, dim3(192), dim3(256), 0, stream, Whh, WhhT);
    hipLaunchKernelGGL(disc_kernel, dim3(kB), dim3(512), 0, stream,
                       x, y, U, S, A, Wih, bih, bhh, Wd, bd, WhhT, out_o, out_p);
}

// Round 13
// 4281.001 us; speedup vs baseline: 1.0699x; 1.0699x over previous
//
#include <hip/hip_runtime.h>
#include <math.h>

constexpr int kB  = 256;
constexpr int kT  = 512;
constexpr int kNS = 64;
constexpr int kH  = 128;

__device__ __forceinline__ float sigmoidf_(float v) { return 1.0f / (1.0f + __expf(-v)); }
__device__ __forceinline__ float dot4(float4 a, float4 b) {
    return a.x*b.x + a.y*b.y + a.z*b.z + a.w*b.w;
}

// One-time: transpose Whh[128][384] -> WhhT[384][128] in d_ws.
extern "C" __global__ void __launch_bounds__(256)
whh_transpose(const float* __restrict__ Whh, float* __restrict__ WhhT) {
    const int o = blockIdx.x * 256 + threadIdx.x;   // 0..49151
    const int j = o >> 7, k = o & 127;
    WhhT[o] = Whh[k * 384 + j];
}

// One block (512 threads) per batch row. 3 barriers/step (R11 structure,
// rebalanced):
//   P1: K rows (regs; s read once, hb-selected halves)               -> barrier
//   P2: einsum carry-over? no — einsum stays in P1? (NO: einsum in P1 as R11's
//       PB was after barrier; here kept identical to R11: PB=einsum+GRU)
// NOTE: phases below mirror R11 exactly except: logit partials in P2,
// ns-reduce on waves 5-7, gh 1 row/thread on waves 1-6, prefetch thread 128.
extern "C" __global__ void __launch_bounds__(512, 2)
disc_kernel(const float* __restrict__ x,   const float* __restrict__ y,
            const float* __restrict__ U,   const float* __restrict__ S,
            const float* __restrict__ A,   const float* __restrict__ Wih,
            const float* __restrict__ bih, const float* __restrict__ bhh,
            const float* __restrict__ Wd,  const float* __restrict__ bd,
            const float* __restrict__ WhhT,
            float* __restrict__ out_o,  float* __restrict__ out_p)
{
    const int b    = blockIdx.x;
    const int tid  = threadIdx.x;
    const int lane = tid & 63;
    const int wid  = tid >> 6;
    const int hb   = tid & 1;

    __shared__ __align__(16) float sh_K[768];
    __shared__ __align__(16) float sh_part[512];
    __shared__ __align__(16) float sh_part2[512];
    __shared__ __align__(16) float sh_ns[192];
    __shared__ __align__(16) float sh_gh[384];
    __shared__ __align__(16) float sh_h[2][kH];      // parity double buffer
    __shared__ __align__(16) float sh_s[kNS];
    __shared__ __align__(16) float sh_Wih[4 * 384];
    __shared__ __align__(16) float sh_bih[384];
    __shared__ __align__(16) float sh_bhh[384];
    __shared__ float sh_Wd[384];
    __shared__ float sh_bd[4];
    __shared__ float sh_encA[8];                     // per-wave max of kk_a
    __shared__ float sh_encB[8];                     // per-wave max of kk_b
    __shared__ float sh_lp[8];                       // logit partials [wave*4+m]
    __shared__ __align__(16) float sh_xt[4];
    __shared__ float sh_x2, sh_s2, sh_err;
    __shared__ float sh_yt[2];

    // ---- Persistent register caches (identical layout to R11) ------------
    const float4* S4 = reinterpret_cast<const float4*>(S);
    const float4* U4 = reinterpret_cast<const float4*>(U);

    float4 Sa[16]; float4 Ua; float Ca;       // full K-row = tid
    float4 Sb[8];  float Ub0, Ub1; float Cb;  // half of K-row 512+(tid>>1)
    {
        float ss = 0.f;
#pragma unroll
        for (int j = 0; j < 16; ++j) { Sa[j] = S4[tid * 16 + j]; ss += dot4(Sa[j], Sa[j]); }
        Ua = U4[tid];
        Ca = -0.5f * (dot4(Ua, Ua) + ss);
    }
    const int pbrow = 512 + (tid >> 1);
    {
        float ss = 0.f;
#pragma unroll
        for (int j = 0; j < 8; ++j) { Sb[j] = S4[pbrow * 16 + hb * 8 + j]; ss += dot4(Sb[j], Sb[j]); }
        Ub0 = U[pbrow * 4 + hb * 2 + 0];
        Ub1 = U[pbrow * 4 + hb * 2 + 1];
        Cb = -0.5f * (Ub0*Ub0 + Ub1*Ub1 + ss);
    }
    // Einsum A caches — wave-uniform chunk mapping (conflict-free K broadcast)
    float A1[64];                              // (m=wid>>2, cc=wid&3), n=lane
#pragma unroll
    for (int dd = 0; dd < 64; ++dd)
        A1[dd] = A[((wid >> 2) * 256 + (wid & 3) * 64 + dd) * 64 + lane];
    float A2[32];                              // m=2, cc2=wid>>1, half=wid&1, n=lane
#pragma unroll
    for (int dd = 0; dd < 32; ++dd)
        A2[dd] = A[(512 + (wid >> 1) * 64 + (wid & 1) * 32 + dd) * 64 + lane];

    // P3-wave0 persistent gate state
    float g0 = 0.3333f, g1 = 0.3333f, g2 = 0.3334f;

    // ---- LDS preload -----------------------------------------------------
    for (int i = tid; i < 1536; i += 512) sh_Wih[i] = Wih[i];
    for (int i = tid; i < 384; i += 512) {
        sh_bih[i] = bih[i];
        sh_bhh[i] = bhh[i];
        sh_gh[i]  = bhh[i];                   // gh(t=0) with h=0
        sh_Wd[i]  = (i < 381) ? Wd[i] : 0.f;  // zero-pad cols 381..383
    }
    if (tid < 3) sh_bd[tid] = bd[tid];
    if (tid < kNS) sh_s[tid] = 0.f;
    if (tid < kH)  sh_h[0][tid] = 0.f;
    if (tid == 0) {
        sh_err = 1.0f; sh_s2 = 0.f;
        float4 xv = reinterpret_cast<const float4*>(x)[(size_t)b * kT];
        reinterpret_cast<float4*>(sh_xt)[0] = xv;
        sh_x2 = dot4(xv, xv);
        sh_yt[0] = y[(size_t)b * kT];
    }
    __syncthreads();

    for (int t = 0; t < kT; ++t) {
        const int par  = t & 1;
        const int par1 = (t + 1) & 1;

        // ===== P1: K rows + per-wave enc partials ==========================
        {
            const float scal = -0.5f * (sh_x2 + sh_s2);
            const float4 xt4 = reinterpret_cast<const float4*>(sh_xt)[0];
            const float4* s4 = reinterpret_cast<const float4*>(sh_s);
            float da0 = 0.f, da1 = 0.f, dblo = 0.f, dbhi = 0.f;
#pragma unroll
            for (int j = 0; j < 8; ++j) {
                const float4 sv0 = s4[j];              // s[0..31]
                const float4 sv1 = s4[8 + j];          // s[32..63]
                da0  += dot4(sv0, Sa[j]);
                da1  += dot4(sv1, Sa[8 + j]);
                dblo += dot4(sv0, Sb[j]);              // pairing if hb==0
                dbhi += dot4(sv1, Sb[j]);              // pairing if hb==1
            }
            const float db = hb ? dbhi : dblo;
            const float kk_a = __expf(scal + Ca + dot4(xt4, Ua) + da0 + da1);
            const float xbp  = hb ? (xt4.z*Ub0 + xt4.w*Ub1) : (xt4.x*Ub0 + xt4.y*Ub1);
            const float ph   = db + Cb + xbp;
            const float po   = __shfl_xor(ph, 1, 64);
            const float kk_b = __expf(scal + ph + po);
            sh_K[tid] = kk_a;
            if (hb == 0) sh_K[512 + (tid >> 1)] = kk_b;
            float mA = kk_a, mB = kk_b;
#pragma unroll
            for (int o = 32; o > 0; o >>= 1) {
                mA = fmaxf(mA, __shfl_xor(mA, o, 64));
                mB = fmaxf(mB, __shfl_xor(mB, o, 64));
            }
            if (lane == 0) { sh_encA[wid] = mA; sh_encB[wid] = mB; }
        }
        __syncthreads();                                  // (1)

        // ===== P2: einsum (all) + GRU/logits (0-127) + prefetch (128) ======
        {
            const float4* K4 = reinterpret_cast<const float4*>(sh_K + wid * 64);
            float acc = 0.f;
#pragma unroll
            for (int j = 0; j < 16; ++j) {                // wave-uniform broadcast
                const float4 kv = K4[j];
                acc += kv.x*A1[4*j] + kv.y*A1[4*j+1] + kv.z*A1[4*j+2] + kv.w*A1[4*j+3];
            }
            sh_part[tid] = acc;
            const float4* K4b = reinterpret_cast<const float4*>(
                                    sh_K + 512 + (wid >> 1) * 64 + (wid & 1) * 32);
            float accb = 0.f;
#pragma unroll
            for (int j = 0; j < 8; ++j) {                 // wave-uniform broadcast
                const float4 kv = K4b[j];
                accb += kv.x*A2[4*j] + kv.y*A2[4*j+1] + kv.z*A2[4*j+2] + kv.w*A2[4*j+3];
            }
            sh_part2[tid] = accb;
        }
        if (tid < 128) {
            const float e0 = fmaxf(fmaxf(sh_encA[0], sh_encA[1]), fmaxf(sh_encA[2], sh_encA[3]));
            const float e1 = fmaxf(fmaxf(sh_encA[4], sh_encA[5]), fmaxf(sh_encA[6], sh_encA[7]));
            const float e2 = fmaxf(fmaxf(fmaxf(sh_encB[0], sh_encB[1]), fmaxf(sh_encB[2], sh_encB[3])),
                                   fmaxf(fmaxf(sh_encB[4], sh_encB[5]), fmaxf(sh_encB[6], sh_encB[7])));
            const float er = sh_err;
            const int j = tid;
            const float gir = sh_bih[j]       + e0*sh_Wih[j]        + e1*sh_Wih[384 + j]
                                              + e2*sh_Wih[768 + j]  + er*sh_Wih[1152 + j];
            const float giz = sh_bih[128 + j] + e0*sh_Wih[128 + j]  + e1*sh_Wih[512 + j]
                                              + e2*sh_Wih[896 + j]  + er*sh_Wih[1280 + j];
            const float gin = sh_bih[256 + j] + e0*sh_Wih[256 + j]  + e1*sh_Wih[640 + j]
                                              + e2*sh_Wih[1024 + j] + er*sh_Wih[1408 + j];
            const float r  = sigmoidf_(gir + sh_gh[j]);
            const float z  = sigmoidf_(giz + sh_gh[128 + j]);
            const float nn = tanhf(gin + r * sh_gh[256 + j]);
            const float hn = (1.f - z) * nn + z * sh_h[par][j];
            sh_h[par1][j] = hn;
            // logit partials (Wd row 127 zero-padded), hn already in register
            float l0 = hn * sh_Wd[j*3+0];
            float l1 = hn * sh_Wd[j*3+1];
            float l2 = hn * sh_Wd[j*3+2];
#pragma unroll
            for (int o = 32; o > 0; o >>= 1) {
                l0 += __shfl_xor(l0, o, 64);
                l1 += __shfl_xor(l1, o, 64);
                l2 += __shfl_xor(l2, o, 64);
            }
            if (lane == 0) {
                sh_lp[wid * 4 + 0] = l0;
                sh_lp[wid * 4 + 1] = l1;
                sh_lp[wid * 4 + 2] = l2;
            }
        } else if (tid == 128) {
            if ((t + 1) < kT) {
                float4 xv = reinterpret_cast<const float4*>(x)[(size_t)b * kT + t + 1];
                reinterpret_cast<float4*>(sh_xt)[0] = xv;
                sh_x2 = dot4(xv, xv);
                sh_yt[par1] = y[(size_t)b * kT + t + 1];
            }
        }
        __syncthreads();                                  // (2)

        // ===== P2b: ns-reduce on waves 5-7 (after einsum stores) ===========
        // NOTE: must come after barrier (2) since it reads all waves' parts.
        if (tid >= 320) {
            const int idx = tid - 320;                     // 0..191
            const int m = idx >> 6, n = idx & 63;
            float v;
            if (m == 0)
                v = (sh_part[n]        + sh_part[64 + n])
                  + (sh_part[128 + n]  + sh_part[192 + n]);
            else if (m == 1)
                v = (sh_part[256 + n]  + sh_part[320 + n])
                  + (sh_part[384 + n]  + sh_part[448 + n]);
            else
                v = ((sh_part2[n]        + sh_part2[64 + n])
                  +  (sh_part2[128 + n]  + sh_part2[192 + n]))
                  + ((sh_part2[256 + n]  + sh_part2[320 + n])
                  +  (sh_part2[384 + n]  + sh_part2[448 + n]));
            sh_ns[idx] = v;
        }
        // ===== P3: w0 tail (short) | waves 1-6: gh 1 row/thr (h_{t+1}) =====
        else if (wid == 0) {
            // wait for ns? ns written by waves 5-7 in THIS phase — need order.
            // Solution: wave 0 computes its own ns reads AFTER barrier (3)?
            // No — keep R11 semantics: wave 0 reads sh_ns written LAST step?
            // WRONG. So wave 0 does the mix from sh_part directly (as R11 PE).
            const float theta = sigmoidf_(sh_h[par1][127]);
            const float l0 = sh_lp[0] + sh_lp[4] + sh_bd[0];
            const float l1 = sh_lp[1] + sh_lp[5] + sh_bd[1];
            const float l2 = sh_lp[2] + sh_lp[6] + sh_bd[2];
            const float mx = fmaxf(l0, fmaxf(l1, l2));
            const float x0 = __expf(l0 - mx), x1 = __expf(l1 - mx), x2 = __expf(l2 - mx);
            const float inv = theta / (x0 + x1 + x2);
            const float omt = 1.f - theta;
            g0 = x0*inv + g0*omt;
            g1 = x1*inv + g1*omt;
            g2 = x2*inv + g2*omt;
            const float ns0 = (sh_part[lane]       + sh_part[64 + lane])
                            + (sh_part[128 + lane] + sh_part[192 + lane]);
            const float ns1 = (sh_part[256 + lane] + sh_part[320 + lane])
                            + (sh_part[384 + lane] + sh_part[448 + lane]);
            const float ns2 = ((sh_part2[lane]       + sh_part2[64 + lane])
                            +  (sh_part2[128 + lane] + sh_part2[192 + lane]))
                            + ((sh_part2[256 + lane] + sh_part2[320 + lane])
                            +  (sh_part2[384 + lane] + sh_part2[448 + lane]));
            const float sn = g0*ns0 + g1*ns1 + g2*ns2;
            sh_s[lane] = sn;
            if (lane == 0)
                out_p[(size_t)b * kT + t] = g0*(1.f-g0) + g1*(1.f-g1) + g2*(1.f-g2);
            if (lane == 63) {
                out_o[(size_t)b * kT + t] = sn;
                sh_err = sn - sh_yt[par];
            }
            float ss = sn * sn;
#pragma unroll
            for (int o = 32; o > 0; o >>= 1) ss += __shfl_xor(ss, o, 64);
            if (lane == 0) sh_s2 = ss;
        } else {                                           // waves 1-4: gh rows
            // 256 threads (tid 64..319), rows 0..383: 1.5 rows/thread ->
            // threads 64..255 take 2 rows (u, u+192), threads 256..319 idle-light?
            // Keep it uniform: threads 64..255 (192 thr) x 2 rows, h once/pair.
            if (tid < 256) {
                const int u = tid - 64;                    // 0..191
                const float4* W4a = reinterpret_cast<const float4*>(WhhT) + u * 32;
                const float4* W4b = reinterpret_cast<const float4*>(WhhT) + (u + 192) * 32;
                const float4* h4  = reinterpret_cast<const float4*>(sh_h[par1]);
                float ga = sh_bhh[u], gb = sh_bhh[u + 192];
#pragma unroll 8
                for (int k4 = 0; k4 < 32; ++k4) {
                    const float4 hv = h4[k4];              // read h ONCE per pair
                    ga += dot4(hv, W4a[k4]);
                    gb += dot4(hv, W4b[k4]);
                }
                sh_gh[u] = ga;
                sh_gh[u + 192] = gb;
            }
        }
        __syncthreads();                                  // (3)
    }
}

extern "C" void kernel_launch(void* const* d_in, const int* in_sizes, int n_in,
                              void* d_out, int out_size, void* d_ws, size_t ws_size,
                              hipStream_t stream)
{
    const float* x   = (const float*)d_in[0];
    const float* y   = (const float*)d_in[1];
    const float* U   = (const float*)d_in[2];
    const float* S   = (const float*)d_in[3];
    const float* A   = (const float*)d_in[4];
    const float* Wih = (const float*)d_in[5];
    const float* Whh = (const float*)d_in[6];
    const float* bih = (const float*)d_in[7];
    const float* bhh = (const float*)d_in[8];
    const float* Wd  = (const float*)d_in[9];
    const float* bd  = (const float*)d_in[10];

    float* WhhT  = (float*)d_ws;                 // 49152 floats = 192 KB scratch
    float* out_o = (float*)d_out;                // (B, T) preds
    float* out_p = out_o + kB * kT;              // (B, T, 1) penalties

    hipLaunchKernelGGL(whh_transpose, dim3(192), dim3(256), 0, stream, Whh, WhhT);
    hipLaunchKernelGGL(disc_kernel, dim3(kB), dim3(512), 0, stream,
                       x, y, U, S, A, Wih, bih, bhh, Wd, bd, WhhT, out_o, out_p);
}

// Round 14
// 3947.688 us; speedup vs baseline: 1.1603x; 1.0844x over previous
//
#include <hip/hip_runtime.h>
#include <math.h>

constexpr int kB  = 256;
constexpr int kT  = 512;
constexpr int kNS = 64;
constexpr int kH  = 128;

__device__ __forceinline__ float sigmoidf_(float v) { return 1.0f / (1.0f + __expf(-v)); }
__device__ __forceinline__ float dot4(float4 a, float4 b) {
    return a.x*b.x + a.y*b.y + a.z*b.z + a.w*b.w;
}

// One-time: transpose Whh[128][384] -> WhhT[384][128] in d_ws.
extern "C" __global__ void __launch_bounds__(256)
whh_transpose(const float* __restrict__ Whh, float* __restrict__ WhhT) {
    const int o = blockIdx.x * 256 + threadIdx.x;   // 0..49151
    const int j = o >> 7, k = o & 127;
    WhhT[o] = Whh[k * 384 + j];
}

// One block (512 threads) per batch row. 3 barriers/step (best-known R11):
//   PA: K rows (regs; s read ONCE — both db halves computed, hb-selected) -> barrier
//   PB: einsum (all waves) + distributed GRU (threads 0-127)              -> barrier
//   PE: w0 tail | w1 prefetch | w2-4 gh 2 rows/thr (h read once/pair)     -> barrier
extern "C" __global__ void __launch_bounds__(512, 2)
disc_kernel(const float* __restrict__ x,   const float* __restrict__ y,
            const float* __restrict__ U,   const float* __restrict__ S,
            const float* __restrict__ A,   const float* __restrict__ Wih,
            const float* __restrict__ bih, const float* __restrict__ bhh,
            const float* __restrict__ Wd,  const float* __restrict__ bd,
            const float* __restrict__ WhhT,
            float* __restrict__ out_o,  float* __restrict__ out_p)
{
    const int b    = blockIdx.x;
    const int tid  = threadIdx.x;
    const int lane = tid & 63;
    const int wid  = tid >> 6;
    const int hb   = tid & 1;

    __shared__ __align__(16) float sh_K[768];
    __shared__ __align__(16) float sh_part[512];
    __shared__ __align__(16) float sh_part2[512];
    __shared__ __align__(16) float sh_gh[384];
    __shared__ __align__(16) float sh_h[2][kH];      // parity double buffer
    __shared__ __align__(16) float sh_s[kNS];
    __shared__ __align__(16) float sh_Wih[4 * 384];
    __shared__ __align__(16) float sh_bih[384];
    __shared__ __align__(16) float sh_bhh[384];
    __shared__ float sh_Wd[384];
    __shared__ float sh_bd[4];
    __shared__ float sh_encA[8];                     // per-wave max of kk_a
    __shared__ float sh_encB[8];                     // per-wave max of kk_b
    __shared__ __align__(16) float sh_xt[4];
    __shared__ float sh_x2, sh_s2, sh_err;
    __shared__ float sh_yt[2];

    // ---- Persistent register caches -------------------------------------
    const float4* S4 = reinterpret_cast<const float4*>(S);
    const float4* U4 = reinterpret_cast<const float4*>(U);

    float4 Sa[16]; float4 Ua; float Ca;       // full K-row = tid
    float4 Sb[8];  float Ub0, Ub1; float Cb;  // half of K-row 512+(tid>>1)
    {
        float ss = 0.f;
#pragma unroll
        for (int j = 0; j < 16; ++j) { Sa[j] = S4[tid * 16 + j]; ss += dot4(Sa[j], Sa[j]); }
        Ua = U4[tid];
        Ca = -0.5f * (dot4(Ua, Ua) + ss);
    }
    const int pbrow = 512 + (tid >> 1);
    {
        float ss = 0.f;
#pragma unroll
        for (int j = 0; j < 8; ++j) { Sb[j] = S4[pbrow * 16 + hb * 8 + j]; ss += dot4(Sb[j], Sb[j]); }
        Ub0 = U[pbrow * 4 + hb * 2 + 0];
        Ub1 = U[pbrow * 4 + hb * 2 + 1];
        Cb = -0.5f * (Ub0*Ub0 + Ub1*Ub1 + ss);
    }
    // Einsum A caches — wave-uniform chunk mapping (conflict-free K broadcast)
    float A1[64];                              // (m=wid>>2, cc=wid&3), n=lane
#pragma unroll
    for (int dd = 0; dd < 64; ++dd)
        A1[dd] = A[((wid >> 2) * 256 + (wid & 3) * 64 + dd) * 64 + lane];
    float A2[32];                              // m=2, cc2=wid>>1, half=wid&1, n=lane
#pragma unroll
    for (int dd = 0; dd < 32; ++dd)
        A2[dd] = A[(512 + (wid >> 1) * 64 + (wid & 1) * 32 + dd) * 64 + lane];

    // PE-wave0 persistent gate state
    float g0 = 0.3333f, g1 = 0.3333f, g2 = 0.3334f;

    // ---- LDS preload -----------------------------------------------------
    for (int i = tid; i < 1536; i += 512) sh_Wih[i] = Wih[i];
    for (int i = tid; i < 384; i += 512) {
        sh_bih[i] = bih[i];
        sh_bhh[i] = bhh[i];
        sh_gh[i]  = bhh[i];                   // gh(t=0) with h=0
        sh_Wd[i]  = (i < 381) ? Wd[i] : 0.f;  // zero-pad cols 381..383
    }
    if (tid < 3) sh_bd[tid] = bd[tid];
    if (tid < kNS) sh_s[tid] = 0.f;
    if (tid < kH)  sh_h[0][tid] = 0.f;
    if (tid == 0) {
        sh_err = 1.0f; sh_s2 = 0.f;
        float4 xv = reinterpret_cast<const float4*>(x)[(size_t)b * kT];
        reinterpret_cast<float4*>(sh_xt)[0] = xv;
        sh_x2 = dot4(xv, xv);
        sh_yt[0] = y[(size_t)b * kT];
    }
    __syncthreads();

    for (int t = 0; t < kT; ++t) {
        const int par  = t & 1;
        const int par1 = (t + 1) & 1;

        // ===== PA: K rows + per-wave enc partials ==========================
        // s read ONCE (16 b128); both db pairings computed, selected by hb.
        {
            const float scal = -0.5f * (sh_x2 + sh_s2);
            const float4 xt4 = reinterpret_cast<const float4*>(sh_xt)[0];
            const float4* s4 = reinterpret_cast<const float4*>(sh_s);
            float da0 = 0.f, da1 = 0.f, dblo = 0.f, dbhi = 0.f;
#pragma unroll
            for (int j = 0; j < 8; ++j) {
                const float4 sv0 = s4[j];              // s[0..31]
                const float4 sv1 = s4[8 + j];          // s[32..63]
                da0  += dot4(sv0, Sa[j]);
                da1  += dot4(sv1, Sa[8 + j]);
                dblo += dot4(sv0, Sb[j]);              // pairing if hb==0
                dbhi += dot4(sv1, Sb[j]);              // pairing if hb==1
            }
            const float db = hb ? dbhi : dblo;
            const float kk_a = __expf(scal + Ca + dot4(xt4, Ua) + da0 + da1);
            const float xbp  = hb ? (xt4.z*Ub0 + xt4.w*Ub1) : (xt4.x*Ub0 + xt4.y*Ub1);
            const float ph   = db + Cb + xbp;
            const float po   = __shfl_xor(ph, 1, 64);
            const float kk_b = __expf(scal + ph + po);
            sh_K[tid] = kk_a;
            if (hb == 0) sh_K[512 + (tid >> 1)] = kk_b;
            float mA = kk_a, mB = kk_b;
#pragma unroll
            for (int o = 32; o > 0; o >>= 1) {
                mA = fmaxf(mA, __shfl_xor(mA, o, 64));
                mB = fmaxf(mB, __shfl_xor(mB, o, 64));
            }
            if (lane == 0) { sh_encA[wid] = mA; sh_encB[wid] = mB; }
        }
        __syncthreads();                                  // (1)

        // ===== PB: einsum (all waves) + distributed GRU (threads 0-127) ====
        {
            const float4* K4 = reinterpret_cast<const float4*>(sh_K + wid * 64);
            float acc = 0.f;
#pragma unroll
            for (int j = 0; j < 16; ++j) {                // wave-uniform broadcast
                const float4 kv = K4[j];
                acc += kv.x*A1[4*j] + kv.y*A1[4*j+1] + kv.z*A1[4*j+2] + kv.w*A1[4*j+3];
            }
            sh_part[tid] = acc;
            const float4* K4b = reinterpret_cast<const float4*>(
                                    sh_K + 512 + (wid >> 1) * 64 + (wid & 1) * 32);
            float accb = 0.f;
#pragma unroll
            for (int j = 0; j < 8; ++j) {                 // wave-uniform broadcast
                const float4 kv = K4b[j];
                accb += kv.x*A2[4*j] + kv.y*A2[4*j+1] + kv.z*A2[4*j+2] + kv.w*A2[4*j+3];
            }
            sh_part2[tid] = accb;
        }
        if (tid < 128) {
            const float e0 = fmaxf(fmaxf(sh_encA[0], sh_encA[1]), fmaxf(sh_encA[2], sh_encA[3]));
            const float e1 = fmaxf(fmaxf(sh_encA[4], sh_encA[5]), fmaxf(sh_encA[6], sh_encA[7]));
            const float e2 = fmaxf(fmaxf(fmaxf(sh_encB[0], sh_encB[1]), fmaxf(sh_encB[2], sh_encB[3])),
                                   fmaxf(fmaxf(sh_encB[4], sh_encB[5]), fmaxf(sh_encB[6], sh_encB[7])));
            const float er = sh_err;
            const int j = tid;
            const float gir = sh_bih[j]       + e0*sh_Wih[j]        + e1*sh_Wih[384 + j]
                                              + e2*sh_Wih[768 + j]  + er*sh_Wih[1152 + j];
            const float giz = sh_bih[128 + j] + e0*sh_Wih[128 + j]  + e1*sh_Wih[512 + j]
                                              + e2*sh_Wih[896 + j]  + er*sh_Wih[1280 + j];
            const float gin = sh_bih[256 + j] + e0*sh_Wih[256 + j]  + e1*sh_Wih[640 + j]
                                              + e2*sh_Wih[1024 + j] + er*sh_Wih[1408 + j];
            const float r  = sigmoidf_(gir + sh_gh[j]);
            const float z  = sigmoidf_(giz + sh_gh[128 + j]);
            const float nn = tanhf(gin + r * sh_gh[256 + j]);
            sh_h[par1][j] = (1.f - z) * nn + z * sh_h[par][j];
        }
        __syncthreads();                                  // (2)

        // ===== PE: w0 tail | w1 prefetch | w2-4 gh 2 rows/thr (h_{t+1}) ====
        if (wid == 0) {
            const float hA = sh_h[par1][lane];
            const float hB = sh_h[par1][64 + lane];
            const float theta = sigmoidf_(sh_h[par1][127]);
            float l0 = hA * sh_Wd[lane*3+0] + hB * sh_Wd[(64+lane)*3+0];
            float l1 = hA * sh_Wd[lane*3+1] + hB * sh_Wd[(64+lane)*3+1];
            float l2 = hA * sh_Wd[lane*3+2] + hB * sh_Wd[(64+lane)*3+2];
#pragma unroll
            for (int o = 32; o > 0; o >>= 1) {
                l0 += __shfl_xor(l0, o, 64);
                l1 += __shfl_xor(l1, o, 64);
                l2 += __shfl_xor(l2, o, 64);
            }
            l0 += sh_bd[0]; l1 += sh_bd[1]; l2 += sh_bd[2];
            const float mx = fmaxf(l0, fmaxf(l1, l2));
            const float x0 = __expf(l0 - mx), x1 = __expf(l1 - mx), x2 = __expf(l2 - mx);
            const float inv = theta / (x0 + x1 + x2);
            const float omt = 1.f - theta;
            g0 = x0*inv + g0*omt;
            g1 = x1*inv + g1*omt;
            g2 = x2*inv + g2*omt;
            const float ns0 = (sh_part[lane]       + sh_part[64 + lane])
                            + (sh_part[128 + lane] + sh_part[192 + lane]);
            const float ns1 = (sh_part[256 + lane] + sh_part[320 + lane])
                            + (sh_part[384 + lane] + sh_part[448 + lane]);
            const float ns2 = ((sh_part2[lane]       + sh_part2[64 + lane])
                            +  (sh_part2[128 + lane] + sh_part2[192 + lane]))
                            + ((sh_part2[256 + lane] + sh_part2[320 + lane])
                            +  (sh_part2[384 + lane] + sh_part2[448 + lane]));
            const float sn = g0*ns0 + g1*ns1 + g2*ns2;
            sh_s[lane] = sn;
            if (lane == 0)
                out_p[(size_t)b * kT + t] = g0*(1.f-g0) + g1*(1.f-g1) + g2*(1.f-g2);
            if (lane == 63) {
                out_o[(size_t)b * kT + t] = sn;
                sh_err = sn - sh_yt[par];
            }
            float ss = sn * sn;
#pragma unroll
            for (int o = 32; o > 0; o >>= 1) ss += __shfl_xor(ss, o, 64);
            if (lane == 0) sh_s2 = ss;
        } else if (wid == 1) {
            if (lane == 0 && (t + 1) < kT) {
                float4 xv = reinterpret_cast<const float4*>(x)[(size_t)b * kT + t + 1];
                reinterpret_cast<float4*>(sh_xt)[0] = xv;
                sh_x2 = dot4(xv, xv);
                sh_yt[par1] = y[(size_t)b * kT + t + 1];
            }
        } else if (tid < 320) {                            // waves 2-4: rows u, u+192
            const int u = tid - 128;                       // 0..191
            const float4* W4a = reinterpret_cast<const float4*>(WhhT) + u * 32;
            const float4* W4b = reinterpret_cast<const float4*>(WhhT) + (u + 192) * 32;
            const float4* h4  = reinterpret_cast<const float4*>(sh_h[par1]);
            float ga = sh_bhh[u], gb = sh_bhh[u + 192];
#pragma unroll 8
            for (int k4 = 0; k4 < 32; ++k4) {
                const float4 hv = h4[k4];                  // read h ONCE per pair
                ga += dot4(hv, W4a[k4]);
                gb += dot4(hv, W4b[k4]);
            }
            sh_gh[u] = ga;
            sh_gh[u + 192] = gb;
        }
        __syncthreads();                                  // (3)
    }
}

extern "C" void kernel_launch(void* const* d_in, const int* in_sizes, int n_in,
                              void* d_out, int out_size, void* d_ws, size_t ws_size,
                              hipStream_t stream)
{
    const float* x   = (const float*)d_in[0];
    const float* y   = (const float*)d_in[1];
    const float* U   = (const float*)d_in[2];
    const float* S   = (const float*)d_in[3];
    const float* A   = (const float*)d_in[4];
    const float* Wih = (const float*)d_in[5];
    const float* Whh = (const float*)d_in[6];
    const float* bih = (const float*)d_in[7];
    const float* bhh = (const float*)d_in[8];
    const float* Wd  = (const float*)d_in[9];
    const float* bd  = (const float*)d_in[10];

    float* WhhT  = (float*)d_ws;                 // 49152 floats = 192 KB scratch
    float* out_o = (float*)d_out;                // (B, T) preds
    float* out_p = out_o + kB * kT;              // (B, T, 1) penalties

    hipLaunchKernelGGL(whh_transpose, dim3(192), dim3(256), 0, stream, Whh, WhhT);
    hipLaunchKernelGGL(disc_kernel, dim3(kB), dim3(512), 0, stream,
                       x, y, U, S, A, Wih, bih, bhh, Wd, bd, WhhT, out_o, out_p);
}